// Round 3
// baseline (204.894 us; speedup 1.0000x reference)
//
#include <hip/hip_runtime.h>
#include <math.h>

// N=100000 nodes, E=6400000 edges, avg degree 64.
// out[n] = [cos(th_n), sin(th_n), w_n],  w_n = S_y / max(||S||, eps),
//   S_x = cos(th)*C + sin(th)*S,  S_y = cos(th)*S - sin(th)*C,
//   C_n = sum_{e:dst=n} cos(x[src_e]),  S_n = sum_{e:dst=n} sin(x[src_e]).
//
// Model (R1-R17): rescan latency-bound (R1-R15); R16 bin+accum cellular
// records 175.8->149.9; R17 LDS-staged flush + 32w/CU 149.9->139.2.
// Remaining: cellular [NBIN][NPART][CAP] layout starves accum (76% lane
// util, 1 dependent round/cell, counts[] on critical path) and bin
// flushes 128-record runs with 2 barriers x 3 tiles.
// R18: contiguous per-(partition,shard) record streams. Bin reserves
// 8-aligned runs via atomicAdd on 128 sharded cursors (1 atomic per ~256
// records; ~256 reservations/cursor over the kernel => no same-address
// queuing), flush is one coalesced run; pads filled with zero-records
// (pu[N]=0). Accum reads a dense stream: full lanes, MLP 8, no counts.
// Bin: TILE=4096, BUF=512 (32KB stage), 8 edges/thread (R14 MLP), 2
// tiles/block. Reservation order nondeterministic but fixed-point u64
// accumulation is exact+commutative => bit-identical output.
// Fixed-point u64: addend=(1<<52)|(sin+32768)<<26|(cos+32768), scale
// 2^15; per-node degree << 4096 => no cross-field carry.

#define EPS 1e-12f
#define NPART 16
#define RNODES 6250      // nodes per partition; u64[6250] = 50KB LDS
#define RMAX 6250
#define BLK 1024

// ---- binning (R18) ----
#define NBIN 1024        // bin blocks; chunk = 6256 edges, 2 tiles
#define BINBLK 512
#define TILE 4096        // edges per tile = BINBLK*8
#define BUF 512          // staged records per partition (16*512*4B = 32KB)
#define NSHARD 8         // cursor shards per partition (by blockIdx&7)
#define SCAP 57344       // records per (partition,shard) region (mult 8);
                         // mean 50K+~1K pads, +30 sigma slack
#define OCAP 262144      // overflow insurance (expected 0 used)

static __device__ __forceinline__ unsigned long long pack_cs(float xv) {
    float sn, cs;
    __sincosf(xv, &sn, &cs);
    const int ci = __float2int_rn(cs * 32768.0f);   // [-32768, 32768]
    const int si = __float2int_rn(sn * 32768.0f);
    return (1ull << 52)
         | ((unsigned long long)(unsigned)(si + 32768) << 26)
         | (unsigned long long)(unsigned)(ci + 32768);
}

// ---------------- prep (fallback paths only) ----------------
__global__ __launch_bounds__(256) void prep_pack_kernel(
        const float* __restrict__ x,
        unsigned long long* __restrict__ pu, int N) {
    int i = blockIdx.x * blockDim.x + threadIdx.x;
    if (i < N) pu[i] = pack_cs(x[i]);
}

// ---------------- R18 bin: stage -> reserve -> coalesced run ------------
__global__ __launch_bounds__(BINBLK, 8) void bin_kernel(
        const float* __restrict__ x,
        const int* __restrict__ esrc,
        const int* __restrict__ edst,
        unsigned long long* __restrict__ pu,   // [N+1], pu[N]=0
        unsigned* __restrict__ rreg,           // [NPART*NSHARD][SCAP]
        int* __restrict__ gctrl,               // [0..127] cursors, [128] ofc
        unsigned long long* __restrict__ oflow,
        int E, int N) {
    __shared__ unsigned stage[NPART * BUF];
    __shared__ int scur[NPART];

    // folded prep: this block's slice of the packed-addend table
    {
        const int PPB = (N + NBIN) / NBIN;     // covers [0, N] across NBIN
        const int idx = blockIdx.x * PPB + threadIdx.x;
        if (threadIdx.x < PPB && idx <= N)
            pu[idx] = (idx < N) ? pack_cs(x[idx]) : 0ull;
    }
    if (threadIdx.x < NPART) scur[threadIdx.x] = 0;
    __syncthreads();

    const int chunk = (((E + NBIN - 1) / NBIN) + 7) & ~7;
    const int beg = blockIdx.x * chunk;
    const int end = min(beg + chunk, E);
    const int shard = blockIdx.x & (NSHARD - 1);
    int* __restrict__ oflow_cnt = gctrl + 128;
    const int wave = threadIdx.x >> 6;
    const int lane = threadIdx.x & 63;

#define BIN_ONE(dd, ss) do {                                              \
        const unsigned d_ = (unsigned)(dd);                               \
        const unsigned p_ = d_ / RNODES;        /* magic-mul const div */ \
        const unsigned dl_ = d_ - p_ * RNODES;  /* < 6250 < 2^13 */       \
        const unsigned rec_ = ((unsigned)(ss) << 13) | dl_;               \
        const int slot_ = atomicAdd(&scur[p_], 1);                        \
        if (slot_ < BUF) {                                                \
            stage[p_ * BUF + slot_] = rec_;                               \
        } else {                                 /* insurance only */     \
            const int g_ = atomicAdd(oflow_cnt, 1);                       \
            if (g_ < OCAP)                                                \
                oflow[g_] = ((unsigned long long)(unsigned)(ss) << 32)    \
                          | d_;                                           \
        }                                                                 \
    } while (0)

    for (int tbeg = beg; tbeg < end; tbeg += TILE) {
        const int i = tbeg + threadIdx.x * 8;
        if (i + 8 <= end) {
            const int4 da = *(const int4*)&edst[i];
            const int4 db = *(const int4*)&edst[i + 4];
            const int4 sa = *(const int4*)&esrc[i];
            const int4 sb = *(const int4*)&esrc[i + 4];
            BIN_ONE(da.x, sa.x);
            BIN_ONE(da.y, sa.y);
            BIN_ONE(da.z, sa.z);
            BIN_ONE(da.w, sa.w);
            BIN_ONE(db.x, sb.x);
            BIN_ONE(db.y, sb.y);
            BIN_ONE(db.z, sb.z);
            BIN_ONE(db.w, sb.w);
        } else {
            for (int k = i; k < min(i + 8, end); ++k)
                BIN_ONE(edst[k], esrc[k]);
        }
        __syncthreads();
        // flush: wave w exclusively owns partitions 2w, 2w+1
        #pragma unroll
        for (int q = 0; q < 2; ++q) {
            const int p = wave * 2 + q;
            const int sc = min(scur[p], (int)BUF);
            if (sc > 0) {
                const int rsv = (sc + 7) & ~7;      // 8-aligned reservation
                int rb = 0;
                if (lane == 0)
                    rb = atomicAdd(&gctrl[p * NSHARD + shard], rsv);
                rb = __shfl(rb, 0);
                unsigned* __restrict__ dst =
                    rreg + (size_t)(p * NSHARD + shard) * SCAP;
                const int fit = min(rsv, max((int)SCAP - rb, 0));
                for (int k = lane; k < fit; k += 64)
                    dst[rb + k] = (k < sc) ? stage[p * BUF + k]
                                           : ((unsigned)N << 13); // pu[N]=0
                for (int k = fit + lane; k < sc; k += 64) {   // insurance
                    const unsigned rec = stage[p * BUF + k];
                    const int g = atomicAdd(oflow_cnt, 1);
                    if (g < OCAP)
                        oflow[g] = ((unsigned long long)(rec >> 13) << 32)
                                 | (unsigned)(p * RNODES + (rec & 8191u));
                }
            }
            if (lane == 0) scur[p] = 0;
        }
        __syncthreads();
    }
#undef BIN_ONE
}

// ---------------- R18 accum: dense stream, full lanes, MLP 8 ------------
__global__ __launch_bounds__(BLK, 2) void accum_kernel(
        const unsigned long long* __restrict__ pu,
        const unsigned* __restrict__ rreg,
        const int* __restrict__ gctrl,
        const unsigned long long* __restrict__ oflow,
        unsigned long long* __restrict__ partials,   // [NPART*nslice][RNODES]
        int nslice) {
    __shared__ unsigned long long lacc[RMAX];
    const int p = blockIdx.x / nslice;
    const int s = blockIdx.x % nslice;

    for (int k = threadIdx.x; k < RNODES; k += BLK) lacc[k] = 0ull;
    __syncthreads();

    const int wave = threadIdx.x >> 6;
    const int lane = threadIdx.x & 63;
    const int shard = wave >> 1;          // 16 waves -> 8 shards x 2 waves
    const int sub = wave & 1;

    const int cnt = min(gctrl[p * NSHARD + shard], (int)SCAP); // mult of 8
    const unsigned* __restrict__ base =
        rreg + (size_t)(p * NSHARD + shard) * SCAP;
    const int per = (((cnt + nslice - 1) / nslice) + 7) & ~7;
    const int sbeg = s * per;
    const int send = min(sbeg + per, cnt);
    for (int i = sbeg + (sub * 64 + lane) * 8; i < send; i += 128 * 8) {
        const uint4 ra = *(const uint4*)&base[i];
        const uint4 rb4 = *(const uint4*)&base[i + 4];
        // 8 gathers in flight before the first atomic
        const unsigned long long v0 = pu[ra.x >> 13];
        const unsigned long long v1 = pu[ra.y >> 13];
        const unsigned long long v2 = pu[ra.z >> 13];
        const unsigned long long v3 = pu[ra.w >> 13];
        const unsigned long long v4 = pu[rb4.x >> 13];
        const unsigned long long v5 = pu[rb4.y >> 13];
        const unsigned long long v6 = pu[rb4.z >> 13];
        const unsigned long long v7 = pu[rb4.w >> 13];
        atomicAdd(&lacc[ra.x & 8191], v0);
        atomicAdd(&lacc[ra.y & 8191], v1);
        atomicAdd(&lacc[ra.z & 8191], v2);
        atomicAdd(&lacc[ra.w & 8191], v3);
        atomicAdd(&lacc[rb4.x & 8191], v4);
        atomicAdd(&lacc[rb4.y & 8191], v5);
        atomicAdd(&lacc[rb4.z & 8191], v6);
        atomicAdd(&lacc[rb4.w & 8191], v7);
    }

    if (s == 0) {   // overflow insurance; expected count 0
        const int oc = min(gctrl[128], (int)OCAP);
        const unsigned pBeg = (unsigned)(p * RNODES);
        for (int i = threadIdx.x; i < oc; i += BLK) {
            const unsigned long long e = oflow[i];
            const unsigned dl = (unsigned)e - pBeg;
            if (dl < (unsigned)RNODES) atomicAdd(&lacc[dl], pu[e >> 32]);
        }
    }

    __syncthreads();
    unsigned long long* dst = partials + (size_t)blockIdx.x * RNODES;
    for (int k = threadIdx.x; k < RNODES; k += BLK) dst[k] = lacc[k];
}

// ---------------- R15 scatter (ws fallback): partition rescan ------------
__global__ __launch_bounds__(BLK, 2) void scatter_kernel(
        const unsigned long long* __restrict__ pu,
        const int* __restrict__ esrc,
        const int* __restrict__ edst,
        unsigned long long* __restrict__ partials,
        int E, int R, int nslice) {
    __shared__ unsigned long long lacc[RMAX];
    const int p = blockIdx.x / nslice;
    const int s = blockIdx.x % nslice;
    const int pBeg = p * R;

    for (int k = threadIdx.x; k < R; k += BLK) lacc[k] = 0ull;
    __syncthreads();

    const int per = (((E + nslice - 1) / nslice) + 7) & ~7;
    const int beg = s * per;
    const int end = min(beg + per, E);
    const int end8 = beg + (max(end - beg, 0) & ~7);

    for (int i = beg + threadIdx.x * 8; i < end8; i += BLK * 8) {
        const int4 da = *(const int4*)&edst[i];
        const int4 db = *(const int4*)&edst[i + 4];
        const int4 sa = *(const int4*)&esrc[i];
        const int4 sb = *(const int4*)&esrc[i + 4];
        const unsigned dl0 = (unsigned)(da.x - pBeg);
        const unsigned dl1 = (unsigned)(da.y - pBeg);
        const unsigned dl2 = (unsigned)(da.z - pBeg);
        const unsigned dl3 = (unsigned)(da.w - pBeg);
        const unsigned dl4 = (unsigned)(db.x - pBeg);
        const unsigned dl5 = (unsigned)(db.y - pBeg);
        const unsigned dl6 = (unsigned)(db.z - pBeg);
        const unsigned dl7 = (unsigned)(db.w - pBeg);
        const bool h0 = dl0 < (unsigned)R, h1 = dl1 < (unsigned)R;
        const bool h2 = dl2 < (unsigned)R, h3 = dl3 < (unsigned)R;
        const bool h4 = dl4 < (unsigned)R, h5 = dl5 < (unsigned)R;
        const bool h6 = dl6 < (unsigned)R, h7 = dl7 < (unsigned)R;
        unsigned long long v0 = 0, v1 = 0, v2 = 0, v3 = 0;
        unsigned long long v4 = 0, v5 = 0, v6 = 0, v7 = 0;
        if (h0) v0 = pu[sa.x];
        if (h1) v1 = pu[sa.y];
        if (h2) v2 = pu[sa.z];
        if (h3) v3 = pu[sa.w];
        if (h4) v4 = pu[sb.x];
        if (h5) v5 = pu[sb.y];
        if (h6) v6 = pu[sb.z];
        if (h7) v7 = pu[sb.w];
        if (h0) atomicAdd(&lacc[dl0], v0);
        if (h1) atomicAdd(&lacc[dl1], v1);
        if (h2) atomicAdd(&lacc[dl2], v2);
        if (h3) atomicAdd(&lacc[dl3], v3);
        if (h4) atomicAdd(&lacc[dl4], v4);
        if (h5) atomicAdd(&lacc[dl5], v5);
        if (h6) atomicAdd(&lacc[dl6], v6);
        if (h7) atomicAdd(&lacc[dl7], v7);
    }
    for (int i = end8 + threadIdx.x; i < end; i += BLK) {
        const unsigned dl = (unsigned)(edst[i] - pBeg);
        if (dl < (unsigned)R) atomicAdd(&lacc[dl], pu[esrc[i]]);
    }

    __syncthreads();
    unsigned long long* dst = partials + (size_t)blockIdx.x * R;
    for (int k = threadIdx.x; k < R; k += BLK) dst[k] = lacc[k];
}

// ---------------- reduce partials (raw u64 sum) + epilogue ----------------
__global__ __launch_bounds__(256) void reduce_kernel(
        const float* __restrict__ theta,
        const unsigned long long* __restrict__ partials,
        float* __restrict__ out, int N, int R, int nslice) {
    const int n = blockIdx.x * blockDim.x + threadIdx.x;
    if (n >= N) return;
    const int p = n / R;
    const int j = n - p * R;
    const unsigned long long* base = partials + (size_t)p * nslice * R + j;
    unsigned long long t = 0ull;
    #pragma unroll 8
    for (int s = 0; s < nslice; ++s) t += base[(size_t)s * R];
    const long long k  = (long long)(t >> 52);
    const long long cf = (long long)(t & 0x3FFFFFFull);
    const long long sf = (long long)((t >> 26) & 0x3FFFFFFull);
    const float C  = (float)(cf - k * 32768) * (1.0f / 32768.0f);
    const float Sv = (float)(sf - k * 32768) * (1.0f / 32768.0f);
    float sn, cs;
    __sincosf(theta[n], &sn, &cs);
    const float nrm = fmaxf(sqrtf(C * C + Sv * Sv), EPS);
    out[3 * n + 0] = cs;
    out[3 * n + 1] = sn;
    out[3 * n + 2] = (cs * Sv - sn * C) / nrm;
}

// ---------------- R8 fallback: global native atomics ----------------
__global__ __launch_bounds__(256) void prep_acc_kernel(float2* __restrict__ acc, int N) {
    int i = blockIdx.x * blockDim.x + threadIdx.x;
    if (i < N) acc[i] = make_float2(0.0f, 0.0f);
}

__global__ __launch_bounds__(256) void edge_scatter_sincos_kernel(
        const int* __restrict__ esrc,
        const int* __restrict__ edst,
        const float* __restrict__ x,
        float2* __restrict__ acc, int E) {
    const int i = (blockIdx.x * 256 + threadIdx.x) * 4;
    float* accf = (float*)acc;
    for (int k = i; k < min(i + 4, E); ++k) {
        float sn, cs;
        __sincosf(x[esrc[k]], &sn, &cs);
        const int d = edst[k];
        unsafeAtomicAdd(&accf[2 * d],     cs);
        unsafeAtomicAdd(&accf[2 * d + 1], sn);
    }
}

__global__ __launch_bounds__(256) void node_kernel(
        const float* __restrict__ theta,
        const float2* __restrict__ acc,
        float* __restrict__ out, int N) {
    int n = blockIdx.x * blockDim.x + threadIdx.x;
    if (n >= N) return;
    float sn, cs;
    __sincosf(theta[n], &sn, &cs);
    const float2 a = acc[n];
    const float nrm = fmaxf(sqrtf(a.x * a.x + a.y * a.y), EPS);
    out[3 * n + 0] = cs;
    out[3 * n + 1] = sn;
    out[3 * n + 2] = (cs * a.y - sn * a.x) / nrm;
}

extern "C" void kernel_launch(void* const* d_in, const int* in_sizes, int n_in,
                              void* d_out, int out_size, void* d_ws, size_t ws_size,
                              hipStream_t stream) {
    const float* x     = (const float*)d_in[0];
    const float* theta = (const float*)d_in[1];
    const int*   esrc  = (const int*)d_in[2];
    const int*   edst  = (const int*)d_in[3];
    float*       out   = (float*)d_out;

    const int N = in_sizes[0];
    const int E = in_sizes[2];

    // ---------- R18 main path: cursor bin -> dense accumulate ------------
    if (N <= NPART * RNODES && N < (1 << 19)
        && (size_t)(N + 1) <= (size_t)NBIN * BINBLK) {
        const int nslice = 32;                       // accum grid 512 = 2/CU
        const size_t part_bytes = (size_t)NPART * nslice * RNODES * 8ull;
        const size_t pu_bytes   = (((size_t)(N + 1) * 8ull) + 15) & ~(size_t)15;
        const size_t rreg_bytes = (size_t)NPART * NSHARD * SCAP * 4ull;
        const size_t ctl_bytes  = 1024;
        const size_t ofl_bytes  = (size_t)OCAP * 8ull;
        const size_t total = part_bytes + pu_bytes + rreg_bytes + ctl_bytes
                           + ofl_bytes;
        if (ws_size >= total) {
            char* w = (char*)d_ws;
            unsigned long long* partials = (unsigned long long*)w; w += part_bytes;
            unsigned long long* pu       = (unsigned long long*)w; w += pu_bytes;
            unsigned*           rreg     = (unsigned*)w;           w += rreg_bytes;
            int*                gctrl    = (int*)w;                w += ctl_bytes;
            unsigned long long* oflow    = (unsigned long long*)w;

            hipMemsetAsync(gctrl, 0, ctl_bytes, stream);
            bin_kernel<<<NBIN, BINBLK, 0, stream>>>(
                x, esrc, edst, pu, rreg, gctrl, oflow, E, N);
            accum_kernel<<<NPART * nslice, BLK, 0, stream>>>(
                pu, rreg, gctrl, oflow, partials, nslice);
            reduce_kernel<<<(N + 255) / 256, 256, 0, stream>>>(
                theta, partials, out, N, RNODES, nslice);
            return;
        }
    }

    // ---------- R15 fallback: NPART=16 rescan, 32 waves/CU ----------
    {
        const int R = (N + NPART - 1) / NPART;
        const size_t pu_bytes = (size_t)N * sizeof(unsigned long long);
        if (R <= RMAX) {
            for (int nslice : {32, 16, 8}) {
                const size_t part_bytes =
                    (size_t)NPART * nslice * R * sizeof(unsigned long long);
                if (ws_size >= part_bytes + pu_bytes) {
                    unsigned long long* partials = (unsigned long long*)d_ws;
                    unsigned long long* pu =
                        (unsigned long long*)((char*)d_ws + part_bytes);
                    prep_pack_kernel<<<(N + 255) / 256, 256, 0, stream>>>(
                        x, pu, N);
                    scatter_kernel<<<NPART * nslice, BLK, 0, stream>>>(
                        pu, esrc, edst, partials, E, R, nslice);
                    reduce_kernel<<<(N + 255) / 256, 256, 0, stream>>>(
                        theta, partials, out, N, R, nslice);
                    return;
                }
            }
        }
    }

    // ---------- R8 fallback: global native atomics ----------
    float2* acc = (float2*)d_ws;   // 800KB
    prep_acc_kernel<<<(N + 255) / 256, 256, 0, stream>>>(acc, N);
    edge_scatter_sincos_kernel<<<(E + 1023) / 1024, 256, 0, stream>>>(esrc, edst, x, acc, E);
    node_kernel<<<(N + 255) / 256, 256, 0, stream>>>(theta, acc, out, N);
}

// Round 4
// 136.740 us; speedup vs baseline: 1.4984x; 1.4984x over previous
//
#include <hip/hip_runtime.h>
#include <math.h>

// N=100000 nodes, E=6400000 edges, avg degree 64.
// out[n] = [cos(th_n), sin(th_n), w_n],  w_n = S_y / max(||S||, eps),
//   S_x = cos(th)*C + sin(th)*S,  S_y = cos(th)*S - sin(th)*C,
//   C_n = sum_{e:dst=n} cos(x[src_e]),  S_n = sum_{e:dst=n} sin(x[src_e]).
//
// Model (R1-R18): rescan latency-bound (R1-R15). R16 bin+accum cellular
// records 175.8->149.9. R17 LDS-staged flush + 32w/CU 149.9->139.2.
// R18 REGRESSION (204.9): global sharded cursors put device-scope
// atomics (128 counters in 4 cache lines, lane0+shfl+barrier) on the
// flush critical path -> bin 89us. Lesson: block-private cells + LDS
// cursors are load-bearing; NO cross-block atomics in the hot path.
// R19: revert to R17 cellular layout; single cumulative stage. chunk =
// E/NBIN = 6250 edges/block, mean 391+-19 records/partition fits BUF=512
// (6.3 sigma) -> stage ALL edges, ONE barrier, ONE coalesced ~391-run
// flush per partition (R17 had 3 tiles x 2 barriers + 128-run flushes).
// Mid-stage overflow -> exact insurance list (expected 0). Accum/reduce
// byte-identical to R17. Fixed-point u64 sums commutative+exact =>
// bit-identical output.
// Fixed-point u64: addend=(1<<52)|(sin+32768)<<26|(cos+32768), scale
// 2^15; per-node-per-slice degree << 4096 => no cross-field carry.

#define EPS 1e-12f
#define NPART 16
#define RNODES 6250      // nodes per partition; u64[6250] = 50KB LDS
#define RMAX 6250
#define BLK 1024

// ---- binning (R19) ----
#define NBIN 1024        // bin blocks; chunk = ceil4(E/NBIN) = 6252 edges
#define BINBLK 512
#define CAP 512          // records per (bin-block, partition) cell;
                         // mean 391, sigma ~19 => +6.3 sigma slack
#define BUF 512          // staged records per partition (16*512*4B = 32KB)
#define OCAP 262144      // overflow insurance (expected 0 used)

static __device__ __forceinline__ unsigned long long pack_cs(float xv) {
    float sn, cs;
    __sincosf(xv, &sn, &cs);
    const int ci = __float2int_rn(cs * 32768.0f);   // [-32768, 32768]
    const int si = __float2int_rn(sn * 32768.0f);
    return (1ull << 52)
         | ((unsigned long long)(unsigned)(si + 32768) << 26)
         | (unsigned long long)(unsigned)(ci + 32768);
}

// ---------------- prep (fallback paths only) ----------------
__global__ __launch_bounds__(256) void prep_pack_kernel(
        const float* __restrict__ x,
        unsigned long long* __restrict__ pu, int N) {
    int i = blockIdx.x * blockDim.x + threadIdx.x;
    if (i < N) pu[i] = pack_cs(x[i]);
}

// ---------------- R19 bin: single stage -> single coalesced flush -------
__global__ __launch_bounds__(BINBLK, 8) void bin_kernel(
        const float* __restrict__ x,
        const int* __restrict__ esrc,
        const int* __restrict__ edst,
        unsigned long long* __restrict__ pu,   // [N+1], pu[N]=0
        unsigned* __restrict__ records,        // [NBIN][NPART][CAP]
        int* __restrict__ counts,              // [NBIN][NPART]
        unsigned long long* __restrict__ oflow,
        int* __restrict__ oflow_cnt,
        int E, int N) {
    __shared__ unsigned stage[NPART * BUF];    // 32KB: whole chunk fits
    __shared__ int scur[NPART];

    // folded prep: this block's slice of the packed-addend table
    {
        const int PPB = (N + NBIN) / NBIN;     // covers [0, N] across NBIN
        const int idx = blockIdx.x * PPB + threadIdx.x;
        if (threadIdx.x < PPB && idx <= N)
            pu[idx] = (idx < N) ? pack_cs(x[idx]) : 0ull;
    }
    if (threadIdx.x < NPART) scur[threadIdx.x] = 0;
    __syncthreads();

    const int chunk = (((E + NBIN - 1) / NBIN) + 3) & ~3;   // 16B-aligned
    const int beg = blockIdx.x * chunk;
    const int end = min(beg + chunk, E);
    const int end4 = beg + (max(end - beg, 0) & ~3);
    unsigned* __restrict__ myrec =
        records + (size_t)blockIdx.x * (NPART * CAP);
    const int wave = threadIdx.x >> 6;
    const int lane = threadIdx.x & 63;

#define BIN_ONE(dd, ss) do {                                              \
        const unsigned d_ = (unsigned)(dd);                               \
        const unsigned p_ = d_ / RNODES;        /* magic-mul const div */ \
        const unsigned dl_ = d_ - p_ * RNODES;  /* < 6250 < 2^13 */       \
        const unsigned rec_ = ((unsigned)(ss) << 13) | dl_;               \
        const int slot_ = atomicAdd(&scur[p_], 1);                        \
        if (slot_ < BUF) {                                                \
            stage[p_ * BUF + slot_] = rec_;                               \
        } else {                                 /* insurance only */     \
            const int g_ = atomicAdd(oflow_cnt, 1);                       \
            if (g_ < OCAP)                                                \
                oflow[g_] = ((unsigned long long)(unsigned)(ss) << 32)    \
                          | d_;                                           \
        }                                                                 \
    } while (0)

    // stage the ENTIRE chunk: no mid barriers, no mid flushes
    for (int i = beg + threadIdx.x * 4; i < end4; i += BINBLK * 4) {
        const int4 d4 = *(const int4*)&edst[i];
        const int4 s4 = *(const int4*)&esrc[i];
        BIN_ONE(d4.x, s4.x);
        BIN_ONE(d4.y, s4.y);
        BIN_ONE(d4.z, s4.z);
        BIN_ONE(d4.w, s4.w);
    }
    for (int i = end4 + threadIdx.x; i < end; i += BINBLK)
        BIN_ONE(edst[i], esrc[i]);
#undef BIN_ONE

    __syncthreads();
    // single flush: wave w exclusively owns partitions 2w, 2w+1
    #pragma unroll
    for (int q = 0; q < 2; ++q) {
        const int p = wave * 2 + q;
        const int sc = min(scur[p], (int)BUF);
        const int c8 = min((sc + 7) & ~7, (int)CAP);    // pad to x8
        for (int k = lane; k < c8; k += 64)
            myrec[p * CAP + k] = (k < sc) ? stage[p * BUF + k]
                                          : ((unsigned)N << 13); // pu[N]=0
        if (lane == 0) counts[blockIdx.x * NPART + p] = c8;
    }
}

// ---------------- accum (R17, unchanged): hits-only, 8 records/lane -----
__global__ __launch_bounds__(BLK, 2) void accum_kernel(
        const unsigned long long* __restrict__ pu,
        const unsigned* __restrict__ records,
        const int* __restrict__ counts,
        const unsigned long long* __restrict__ oflow,
        const int* __restrict__ oflow_cnt,
        unsigned long long* __restrict__ partials,   // [NPART*nslice][RNODES]
        int nslice) {
    __shared__ unsigned long long lacc[RMAX];
    const int p = blockIdx.x / nslice;
    const int s = blockIdx.x % nslice;   // XCD = s%8, matches bin b%8

    for (int k = threadIdx.x; k < RNODES; k += BLK) lacc[k] = 0ull;
    __syncthreads();

    const int wave = threadIdx.x >> 6;
    const int lane = threadIdx.x & 63;
    const int wstep = (BLK / 64) * nslice;
    for (int c = s + wave * nslice; c < NBIN; c += wstep) {
        const int cnt = counts[c * NPART + p];       // multiple of 8
        const unsigned* __restrict__ base =
            records + ((size_t)(c * NPART + p)) * CAP;
        for (int i = lane * 8; i < cnt; i += 64 * 8) {
            const uint4 ra = *(const uint4*)&base[i];
            const uint4 rb = *(const uint4*)&base[i + 4];
            // 8 gathers in flight before the first atomic
            const unsigned long long v0 = pu[ra.x >> 13];
            const unsigned long long v1 = pu[ra.y >> 13];
            const unsigned long long v2 = pu[ra.z >> 13];
            const unsigned long long v3 = pu[ra.w >> 13];
            const unsigned long long v4 = pu[rb.x >> 13];
            const unsigned long long v5 = pu[rb.y >> 13];
            const unsigned long long v6 = pu[rb.z >> 13];
            const unsigned long long v7 = pu[rb.w >> 13];
            atomicAdd(&lacc[ra.x & 8191], v0);
            atomicAdd(&lacc[ra.y & 8191], v1);
            atomicAdd(&lacc[ra.z & 8191], v2);
            atomicAdd(&lacc[ra.w & 8191], v3);
            atomicAdd(&lacc[rb.x & 8191], v4);
            atomicAdd(&lacc[rb.y & 8191], v5);
            atomicAdd(&lacc[rb.z & 8191], v6);
            atomicAdd(&lacc[rb.w & 8191], v7);
        }
    }

    if (s == 0) {   // overflow insurance; expected count 0
        const int oc = min(*oflow_cnt, (int)OCAP);
        const unsigned pBeg = (unsigned)(p * RNODES);
        for (int i = threadIdx.x; i < oc; i += BLK) {
            const unsigned long long e = oflow[i];
            const unsigned dl = (unsigned)e - pBeg;
            if (dl < (unsigned)RNODES) atomicAdd(&lacc[dl], pu[e >> 32]);
        }
    }

    __syncthreads();
    unsigned long long* dst = partials + (size_t)blockIdx.x * RNODES;
    for (int k = threadIdx.x; k < RNODES; k += BLK) dst[k] = lacc[k];
}

// ---------------- R15 scatter (ws fallback): partition rescan ------------
__global__ __launch_bounds__(BLK, 2) void scatter_kernel(
        const unsigned long long* __restrict__ pu,
        const int* __restrict__ esrc,
        const int* __restrict__ edst,
        unsigned long long* __restrict__ partials,
        int E, int R, int nslice) {
    __shared__ unsigned long long lacc[RMAX];
    const int p = blockIdx.x / nslice;
    const int s = blockIdx.x % nslice;
    const int pBeg = p * R;

    for (int k = threadIdx.x; k < R; k += BLK) lacc[k] = 0ull;
    __syncthreads();

    const int per = (((E + nslice - 1) / nslice) + 7) & ~7;
    const int beg = s * per;
    const int end = min(beg + per, E);
    const int end8 = beg + (max(end - beg, 0) & ~7);

    for (int i = beg + threadIdx.x * 8; i < end8; i += BLK * 8) {
        const int4 da = *(const int4*)&edst[i];
        const int4 db = *(const int4*)&edst[i + 4];
        const int4 sa = *(const int4*)&esrc[i];
        const int4 sb = *(const int4*)&esrc[i + 4];
        const unsigned dl0 = (unsigned)(da.x - pBeg);
        const unsigned dl1 = (unsigned)(da.y - pBeg);
        const unsigned dl2 = (unsigned)(da.z - pBeg);
        const unsigned dl3 = (unsigned)(da.w - pBeg);
        const unsigned dl4 = (unsigned)(db.x - pBeg);
        const unsigned dl5 = (unsigned)(db.y - pBeg);
        const unsigned dl6 = (unsigned)(db.z - pBeg);
        const unsigned dl7 = (unsigned)(db.w - pBeg);
        const bool h0 = dl0 < (unsigned)R, h1 = dl1 < (unsigned)R;
        const bool h2 = dl2 < (unsigned)R, h3 = dl3 < (unsigned)R;
        const bool h4 = dl4 < (unsigned)R, h5 = dl5 < (unsigned)R;
        const bool h6 = dl6 < (unsigned)R, h7 = dl7 < (unsigned)R;
        unsigned long long v0 = 0, v1 = 0, v2 = 0, v3 = 0;
        unsigned long long v4 = 0, v5 = 0, v6 = 0, v7 = 0;
        if (h0) v0 = pu[sa.x];
        if (h1) v1 = pu[sa.y];
        if (h2) v2 = pu[sa.z];
        if (h3) v3 = pu[sa.w];
        if (h4) v4 = pu[sb.x];
        if (h5) v5 = pu[sb.y];
        if (h6) v6 = pu[sb.z];
        if (h7) v7 = pu[sb.w];
        if (h0) atomicAdd(&lacc[dl0], v0);
        if (h1) atomicAdd(&lacc[dl1], v1);
        if (h2) atomicAdd(&lacc[dl2], v2);
        if (h3) atomicAdd(&lacc[dl3], v3);
        if (h4) atomicAdd(&lacc[dl4], v4);
        if (h5) atomicAdd(&lacc[dl5], v5);
        if (h6) atomicAdd(&lacc[dl6], v6);
        if (h7) atomicAdd(&lacc[dl7], v7);
    }
    for (int i = end8 + threadIdx.x; i < end; i += BLK) {
        const unsigned dl = (unsigned)(edst[i] - pBeg);
        if (dl < (unsigned)R) atomicAdd(&lacc[dl], pu[esrc[i]]);
    }

    __syncthreads();
    unsigned long long* dst = partials + (size_t)blockIdx.x * R;
    for (int k = threadIdx.x; k < R; k += BLK) dst[k] = lacc[k];
}

// ---------------- reduce partials (raw u64 sum) + epilogue ----------------
__global__ __launch_bounds__(256) void reduce_kernel(
        const float* __restrict__ theta,
        const unsigned long long* __restrict__ partials,
        float* __restrict__ out, int N, int R, int nslice) {
    const int n = blockIdx.x * blockDim.x + threadIdx.x;
    if (n >= N) return;
    const int p = n / R;
    const int j = n - p * R;
    const unsigned long long* base = partials + (size_t)p * nslice * R + j;
    unsigned long long t = 0ull;
    #pragma unroll 8
    for (int s = 0; s < nslice; ++s) t += base[(size_t)s * R];
    const long long k  = (long long)(t >> 52);
    const long long cf = (long long)(t & 0x3FFFFFFull);
    const long long sf = (long long)((t >> 26) & 0x3FFFFFFull);
    const float C  = (float)(cf - k * 32768) * (1.0f / 32768.0f);
    const float Sv = (float)(sf - k * 32768) * (1.0f / 32768.0f);
    float sn, cs;
    __sincosf(theta[n], &sn, &cs);
    const float nrm = fmaxf(sqrtf(C * C + Sv * Sv), EPS);
    out[3 * n + 0] = cs;
    out[3 * n + 1] = sn;
    out[3 * n + 2] = (cs * Sv - sn * C) / nrm;
}

// ---------------- R8 fallback: global native atomics ----------------
__global__ __launch_bounds__(256) void prep_acc_kernel(float2* __restrict__ acc, int N) {
    int i = blockIdx.x * blockDim.x + threadIdx.x;
    if (i < N) acc[i] = make_float2(0.0f, 0.0f);
}

__global__ __launch_bounds__(256) void edge_scatter_sincos_kernel(
        const int* __restrict__ esrc,
        const int* __restrict__ edst,
        const float* __restrict__ x,
        float2* __restrict__ acc, int E) {
    const int i = (blockIdx.x * 256 + threadIdx.x) * 4;
    float* accf = (float*)acc;
    for (int k = i; k < min(i + 4, E); ++k) {
        float sn, cs;
        __sincosf(x[esrc[k]], &sn, &cs);
        const int d = edst[k];
        unsafeAtomicAdd(&accf[2 * d],     cs);
        unsafeAtomicAdd(&accf[2 * d + 1], sn);
    }
}

__global__ __launch_bounds__(256) void node_kernel(
        const float* __restrict__ theta,
        const float2* __restrict__ acc,
        float* __restrict__ out, int N) {
    int n = blockIdx.x * blockDim.x + threadIdx.x;
    if (n >= N) return;
    float sn, cs;
    __sincosf(theta[n], &sn, &cs);
    const float2 a = acc[n];
    const float nrm = fmaxf(sqrtf(a.x * a.x + a.y * a.y), EPS);
    out[3 * n + 0] = cs;
    out[3 * n + 1] = sn;
    out[3 * n + 2] = (cs * a.y - sn * a.x) / nrm;
}

extern "C" void kernel_launch(void* const* d_in, const int* in_sizes, int n_in,
                              void* d_out, int out_size, void* d_ws, size_t ws_size,
                              hipStream_t stream) {
    const float* x     = (const float*)d_in[0];
    const float* theta = (const float*)d_in[1];
    const int*   esrc  = (const int*)d_in[2];
    const int*   edst  = (const int*)d_in[3];
    float*       out   = (float*)d_out;

    const int N = in_sizes[0];
    const int E = in_sizes[2];

    // ---------- R19 main path: single-stage bin -> hits-only accum -------
    if (N <= NPART * RNODES && N < (1 << 19)
        && (size_t)(N + 1) <= (size_t)NBIN * BINBLK) {
        const int nslice = 32;                       // accum grid 512 = 2/CU
        const size_t part_bytes = (size_t)NPART * nslice * RNODES * 8ull;
        const size_t pu_bytes   = (((size_t)(N + 1) * 8ull) + 15) & ~(size_t)15;
        const size_t rec_bytes  = (size_t)NBIN * NPART * CAP * 4ull;
        const size_t cnt_bytes  = (size_t)NBIN * NPART * 4ull;
        const size_t ofc_bytes  = 64;
        const size_t ofl_bytes  = (size_t)OCAP * 8ull;
        const size_t total = part_bytes + pu_bytes + rec_bytes + cnt_bytes
                           + ofc_bytes + ofl_bytes;
        if (ws_size >= total) {
            char* w = (char*)d_ws;
            unsigned long long* partials = (unsigned long long*)w; w += part_bytes;
            unsigned long long* pu       = (unsigned long long*)w; w += pu_bytes;
            unsigned*           records  = (unsigned*)w;           w += rec_bytes;
            int*                counts   = (int*)w;                w += cnt_bytes;
            int*                oflow_cnt= (int*)w;                w += ofc_bytes;
            unsigned long long* oflow    = (unsigned long long*)w;

            hipMemsetAsync(oflow_cnt, 0, sizeof(int), stream);
            bin_kernel<<<NBIN, BINBLK, 0, stream>>>(
                x, esrc, edst, pu, records, counts, oflow, oflow_cnt, E, N);
            accum_kernel<<<NPART * nslice, BLK, 0, stream>>>(
                pu, records, counts, oflow, oflow_cnt, partials, nslice);
            reduce_kernel<<<(N + 255) / 256, 256, 0, stream>>>(
                theta, partials, out, N, RNODES, nslice);
            return;
        }
    }

    // ---------- R15 fallback: NPART=16 rescan, 32 waves/CU ----------
    {
        const int R = (N + NPART - 1) / NPART;
        const size_t pu_bytes = (size_t)N * sizeof(unsigned long long);
        if (R <= RMAX) {
            for (int nslice : {32, 16, 8}) {
                const size_t part_bytes =
                    (size_t)NPART * nslice * R * sizeof(unsigned long long);
                if (ws_size >= part_bytes + pu_bytes) {
                    unsigned long long* partials = (unsigned long long*)d_ws;
                    unsigned long long* pu =
                        (unsigned long long*)((char*)d_ws + part_bytes);
                    prep_pack_kernel<<<(N + 255) / 256, 256, 0, stream>>>(
                        x, pu, N);
                    scatter_kernel<<<NPART * nslice, BLK, 0, stream>>>(
                        pu, esrc, edst, partials, E, R, nslice);
                    reduce_kernel<<<(N + 255) / 256, 256, 0, stream>>>(
                        theta, partials, out, N, R, nslice);
                    return;
                }
            }
        }
    }

    // ---------- R8 fallback: global native atomics ----------
    float2* acc = (float2*)d_ws;   // 800KB
    prep_acc_kernel<<<(N + 255) / 256, 256, 0, stream>>>(acc, N);
    edge_scatter_sincos_kernel<<<(E + 1023) / 1024, 256, 0, stream>>>(esrc, edst, x, acc, E);
    node_kernel<<<(N + 255) / 256, 256, 0, stream>>>(theta, acc, out, N);
}